// Round 23
// baseline (275.204 us; speedup 1.0000x reference)
//
#include <hip/hip_runtime.h>

// SceneGraphModel, single-bf16 MFMA, barrier-free per-wave pipeline.
// Round-23 (base r21; r22's tail-weights-to-LDS regressed +7.3us, reverted):
// PERSISTENT GRID-STRIDE, ZERO NEW VGPRS. r19's persistent spilled because
// of the gather-PREFETCH registers (+10 live VGPRs); persistence itself is
// free: loop induction t/eBase are wave-uniform -> SGPRs. Grid=1024 blocks
// (2 passes at 2 blocks/CU), weights staged + sync ONCE, no barriers inside
// the loop (sF per-wave private; same-wave DS ops in-order across iters).
// Prologues 3907 -> 1024 (r21's halving 7813->3907 bought 7.5us).
// History: r5 nt-store amp; r6/r12/r19 spills; r15 occupancy falsified;
// r16 weights->LDS -11; r17 null; r18 wt-stationary -8; r20 unclamp worse;
// r21 block512 -7.5 (177.5); r22 tail-wt-LDS +7.3 (reverted).

typedef __attribute__((ext_vector_type(8))) short bf16x8;   // 8 bf16 = 4 VGPR
typedef __attribute__((ext_vector_type(4))) float f32x4;

#define UNROLL _Pragma("unroll")
#define PRIO_HI __builtin_amdgcn_s_setprio(1)
#define PRIO_LO __builtin_amdgcn_s_setprio(0)

__device__ __forceinline__ unsigned fbits(float x) {
    union { float f; unsigned u; } v; v.f = x; return v.u;
}
// pack two f32 -> two bf16 (truncation; rel err 2^-8, fine vs thresholds)
__device__ __forceinline__ unsigned pk2t(float a, float b) {
    return (fbits(a) >> 16) | (fbits(b) & 0xffff0000u);
}
__device__ __forceinline__ unsigned short bf16rne(float x) {
    unsigned u = fbits(x);
    unsigned r = u + 0x7fffu + ((u >> 16) & 1u);
    return (unsigned short)(r >> 16);
}

__device__ __forceinline__ f32x4 mfma1(bf16x8 a, bf16x8 b, f32x4 acc) {
    return __builtin_amdgcn_mfma_f32_16x16x32_bf16(a, b, acc, 0, 0, 0);
}

__device__ __forceinline__ f32x4 bias4(const float* __restrict__ b, int nt, int g) {
    const float4 v = *(const float4*)(b + nt * 16 + g * 4);
    f32x4 r; r[0] = v.x; r[1] = v.y; r[2] = v.z; r[3] = v.w; return r;
}

// Store one lane's 4 consecutive-k values (bf16) into B-frag-order LDS tile.
// Element (row lr, k) lives at short index (lr + 16*(k>>3))*8 + (k&7).
__device__ __forceinline__ void chunk_store(unsigned short* __restrict__ tile,
                                            int lr, int klb, f32x4 a) {
    uint2 v; v.x = pk2t(a[0], a[1]); v.y = pk2t(a[2], a[3]);
    const int lanep = lr + 16 * (klb >> 3);
    *(uint2*)(tile + lanep * 8 + (klb & 7)) = v;
}

// B-frag load where k16..31 is the constant bias pattern: lanes g<2 read the
// staged k0..15; lane g==2 composes (k16=1.0,0..), g==3 all zeros.
__device__ __forceinline__ bf16x8 frag_or_const(const unsigned short* __restrict__ tile,
                                                int g, int lid, unsigned k16w) {
    union { bf16x8 v; uint4 u; } t;
    if (g < 2) {
        t.u = *(const uint4*)(tile + lid * 8);
    } else {
        t.u.x = k16w; t.u.y = 0u; t.u.z = 0u; t.u.w = 0u;
    }
    return t.v;
}

// ---- weight prep: bf16(RNE) + fragment-swizzle into d_ws ----
// frag element: lane l holds W[k][n], k = kt*32 + (l>>4)*8 + j, n = nt*16 + (l&15)
// W0 @0 (8 nt, k=16 row carries ob0), W1 @4096, W2 @12288, W3 @14336,
// W7 (rW2/rb2) B-frags @14848 (4 nt; k0-3 = rW2, k4 = rb2),
// W5 (rW0/rb0) @16896 (k0-15 = rW0, k16 = rb0), W6 (rW1/rb1) @17408.
__global__ __launch_bounds__(256) void sg_prep(
    const float* __restrict__ oW0, const float* __restrict__ ob0,
    const float* __restrict__ oW1, const float* __restrict__ oW2,
    const float* __restrict__ oW3,
    const float* __restrict__ rW0, const float* __restrict__ rb0,
    const float* __restrict__ rW1, const float* __restrict__ rb1,
    const float* __restrict__ rW2, const float* __restrict__ rb2,
    unsigned short* __restrict__ wsp)
{
    const int idx = blockIdx.x * 256 + threadIdx.x;
    if (idx >= 17920) return;
    if (idx >= 16896) {   // W5 / W6 tail-layer frags
        const int t2 = idx - 16896;
        const int tile = t2 >> 9;
        const int l = (t2 >> 3) & 63, j = t2 & 7;
        const int k = (l >> 4) * 8 + j;
        const int n = l & 15;
        float v = 0.0f;
        if (tile == 0) {          // 16->8: rW0 [16x8], rb0
            if (n < 8) { if (k < 16) v = rW0[k * 8 + n]; else if (k == 16) v = rb0[n]; }
        } else {                  // 8->4: rW1 [8x4], rb1
            if (n < 4) { if (k < 8) v = rW1[k * 4 + n]; else if (k == 16) v = rb1[n]; }
        }
        wsp[idx] = bf16rne(v);
        return;
    }
    if (idx >= 14848) {   // final-layer B-frags: B[k][n], n = class col
        const int t2 = idx - 14848;
        const int nt = t2 >> 9;
        const int l = (t2 >> 3) & 63, j = t2 & 7;
        const int k = (l >> 4) * 8 + j;
        const int n = nt * 16 + (l & 15);
        float v = 0.0f;
        if (n < 51) {
            if (k < 4)       v = rW2[k * 51 + n];
            else if (k == 4) v = rb2[n];
        }
        wsp[idx] = bf16rne(v);
        return;
    }
    int t = idx, K, N, kt, nt;
    const float* W;
    bool isW0 = false;
    if (t < 4096)        { W = oW0; K = 16;  N = 128; kt = 0; nt = t >> 9; isW0 = true; }
    else if (t < 12288)  { t -= 4096;  W = oW1; K = 128; N = 64; int f = t >> 9; kt = f >> 2; nt = f & 3; }
    else if (t < 14336)  { t -= 12288; W = oW2; K = 64;  N = 32; int f = t >> 9; kt = f >> 1; nt = f & 1; }
    else                 { t -= 14336; W = oW3; K = 32;  N = 16; kt = 0; nt = 0; }
    const int lid = (t >> 3) & 63, j = t & 7;
    const int k = kt * 32 + (lid >> 4) * 8 + j;
    const int n = nt * 16 + (lid & 15);
    float w = 0.0f;
    if (k < K)                w = W[(size_t)k * N + n];
    else if (isW0 && k == 16) w = ob0[n];          // bias row (h0 k=16 staged as 1.0)
    wsp[idx] = bf16rne(w);
}

__global__ __launch_bounds__(512, 4) void sg_mfma(
    const float* __restrict__ obj, const int* __restrict__ rel,
    const int* __restrict__ pairs,
    const unsigned short* __restrict__ wsp,
    const float* __restrict__ ob1, const float* __restrict__ ob2,
    const float* __restrict__ ob3,
    float* __restrict__ out, float* __restrict__ out_rel, int E)
{
    // LDS: [0,24K) block-shared W0+W1 frags (staged ONCE); [24K,56K) per-wave
    // 4 KB frag buffers. 56 KB/block = 2 blocks/CU, 4 waves/SIMD.
    __shared__ unsigned char smem[24576 + 8 * 4096];
    const int tid = threadIdx.x;
    const int lid = tid & 63;
    const int wid = tid >> 6;
    const int g = lid >> 4, lr = lid & 15;
    unsigned short* wL = (unsigned short*)smem;
    unsigned short* sF = (unsigned short*)(smem + 24576 + wid * 4096);
    const unsigned k16w = (g == 2) ? 0x00003f80u : 0u;   // bf16(1.0) at k16
    const f32x4 z = {0.0f, 0.0f, 0.0f, 0.0f};

    // ---- one-time cooperative stage of W0+W1 frags (24 KB = 1536 uint4) ----
    {
        const uint4* src = (const uint4*)wsp;
        uint4* dst = (uint4*)smem;
        UNROLL for (int i = 0; i < 3; ++i)
            dst[tid + i * 512] = src[tid + i * 512];
    }
    __syncthreads();   // once; no barriers inside the loop

    const int T = (E + 511) / 512;

    for (int tt = blockIdx.x; tt < T; tt += gridDim.x) {
        const long long eBase = (long long)tt * 512;
        const long long ee = eBase + tid;
        const int e = (ee < E) ? (int)ee : (E - 1);

        // ---- stage h0 k0..15 (k16..31 composed in registers at read) ----
        {
            const int2 pr = *(const int2*)(pairs + 2 * e);
            const float4* pa = (const float4*)(obj + (size_t)pr.x * 8);
            const float4* pb = (const float4*)(obj + (size_t)pr.y * 8);
            const float4 v0 = pa[0], v1 = pa[1], v2 = pb[0], v3 = pb[1];
            uint4 c0, c1;
            c0.x = pk2t(v0.x, v0.y); c0.y = pk2t(v0.z, v0.w);
            c0.z = pk2t(v1.x, v1.y); c0.w = pk2t(v1.z, v1.w);
            c1.x = pk2t(v2.x, v2.y); c1.y = pk2t(v2.z, v2.w);
            c1.z = pk2t(v3.x, v3.y); c1.w = pk2t(v3.z, v3.w);
            unsigned short* dh = sF + g * 512 + lr * 8;
            *(uint4*)(dh)       = c0;   // k 0..7
            *(uint4*)(dh + 128) = c1;   // k 8..15
        }

        // hoist h0 B-frags; g>=2 lanes = constant half
        bf16x8 a0[4];
        UNROLL for (int m = 0; m < 4; ++m)
            a0[m] = frag_or_const(sF + m * 512, g, lid, k16w);

        // ---- layers 1+2 fused over h1 32-col chunks (weight-stationary) ----
        f32x4 acc2[4][4];
        UNROLL for (int m = 0; m < 4; ++m)
            UNROLL for (int n2 = 0; n2 < 4; ++n2) acc2[m][n2] = bias4(ob1, n2, g);

        for (int kt2 = 0; kt2 < 4; ++kt2) {
            const bf16x8 w0a = *(const bf16x8*)(wL + (kt2 * 2 + 0) * 512 + lid * 8);
            const bf16x8 w0b = *(const bf16x8*)(wL + (kt2 * 2 + 1) * 512 + lid * 8);
            UNROLL for (int m = 0; m < 4; ++m) {
                f32x4 a = z, b = z;
                PRIO_HI;
                a = mfma1(w0a, a0[m], a);
                b = mfma1(w0b, a0[m], b);
                PRIO_LO;
                UNROLL for (int jr = 0; jr < 4; ++jr) {
                    a[jr] = fmaxf(a[jr], 0.0f);
                    b[jr] = fmaxf(b[jr], 0.0f);
                }
                chunk_store(sF + m * 512, lr, g * 4, a);
                chunk_store(sF + m * 512, lr, 16 + g * 4, b);
            }
            bf16x8 ah[4];
            UNROLL for (int m = 0; m < 4; ++m)
                ah[m] = *(const bf16x8*)(sF + m * 512 + lid * 8);
            UNROLL for (int n2 = 0; n2 < 4; ++n2) {
                const bf16x8 w = *(const bf16x8*)(wL + 4096 + (kt2 * 4 + n2) * 512 + lid * 8);
                PRIO_HI;
                UNROLL for (int m = 0; m < 4; ++m)
                    acc2[m][n2] = mfma1(w, ah[m], acc2[m][n2]);
                PRIO_LO;
            }
        }

        // relu h2
        UNROLL for (int m = 0; m < 4; ++m)
            UNROLL for (int n2 = 0; n2 < 4; ++n2)
                UNROLL for (int jr = 0; jr < 4; ++jr)
                    acc2[m][n2][jr] = fmaxf(acc2[m][n2][jr], 0.0f);

        // ---- layer 3 over h2 32-col chunks (weights hoisted, global/L1) ----
        f32x4 acc3[4][2];
        UNROLL for (int m = 0; m < 4; ++m)
            UNROLL for (int n3 = 0; n3 < 2; ++n3) acc3[m][n3] = bias4(ob2, n3, g);

        UNROLL for (int kt3 = 0; kt3 < 2; ++kt3) {
            UNROLL for (int m = 0; m < 4; ++m)
                UNROLL for (int ntl = 0; ntl < 2; ++ntl)
                    chunk_store(sF + m * 512, lr, ntl * 16 + g * 4, acc2[m][2 * kt3 + ntl]);
            bf16x8 ah3[4];
            UNROLL for (int m = 0; m < 4; ++m)
                ah3[m] = *(const bf16x8*)(sF + m * 512 + lid * 8);
            UNROLL for (int n3 = 0; n3 < 2; ++n3) {
                const bf16x8 w = *(const bf16x8*)(wsp + 12288 + (size_t)(kt3 * 2 + n3) * 512 + lid * 8);
                PRIO_HI;
                UNROLL for (int m = 0; m < 4; ++m)
                    acc3[m][n3] = mfma1(w, ah3[m], acc3[m][n3]);
                PRIO_LO;
            }
        }

        // ---- layer 4 (32->16, linear) via MFMA ----
        UNROLL for (int m = 0; m < 4; ++m) {
            UNROLL for (int n3 = 0; n3 < 2; ++n3) {
                UNROLL for (int jr = 0; jr < 4; ++jr)
                    acc3[m][n3][jr] = fmaxf(acc3[m][n3][jr], 0.0f);   // relu h3
                chunk_store(sF + m * 512, lr, n3 * 16 + g * 4, acc3[m][n3]);
            }
        }
        const bf16x8 w4 = *(const bf16x8*)(wsp + 14336 + lid * 8);
        f32x4 acc4[4];
        UNROLL for (int m = 0; m < 4; ++m) {
            bf16x8 ah = *(const bf16x8*)(sF + m * 512 + lid * 8);
            PRIO_HI;
            acc4[m] = mfma1(w4, ah, bias4(ob3, 0, g));
            PRIO_LO;
        }

        // hoist tail weight frags (global, L1-resident)
        const bf16x8 w5 = *(const bf16x8*)(wsp + 16896 + lid * 8);
        const bf16x8 w6 = *(const bf16x8*)(wsp + 17408 + lid * 8);

        // ---- layer 5 (16->8, relu): stage h4 k0..15; k16..31 const ----
        UNROLL for (int m = 0; m < 4; ++m)
            chunk_store(sF + m * 512, lr, g * 4, acc4[m]);
        f32x4 acc5[4];
        UNROLL for (int m = 0; m < 4; ++m) {
            bf16x8 b5 = frag_or_const(sF + m * 512, g, lid, k16w);
            PRIO_HI;
            acc5[m] = mfma1(w5, b5, z);                      // bias via k16 row
            PRIO_LO;
            UNROLL for (int r = 0; r < 4; ++r) acc5[m][r] = fmaxf(acc5[m][r], 0.0f);
        }

        // ---- layer 6 (8->4, relu): stage h5 (k8..15 genuine zeros) ----
        UNROLL for (int m = 0; m < 4; ++m)
            chunk_store(sF + m * 512, lr, g * 4, acc5[m]);
        f32x4 acc6[4];
        UNROLL for (int m = 0; m < 4; ++m) {
            bf16x8 b6 = frag_or_const(sF + m * 512, g, lid, k16w);
            PRIO_HI;
            acc6[m] = mfma1(w6, b6, z);
            PRIO_LO;
            UNROLL for (int r = 0; r < 4; ++r) acc6[m][r] = fmaxf(acc6[m][r], 0.0f);
        }

        // ---- final layer 4->51 via MFMA, A-frag from OWN registers ----
        bf16x8 wf[4];
        UNROLL for (int nt = 0; nt < 4; ++nt)
            wf[nt] = *(const bf16x8*)(wsp + 14848 + (size_t)nt * 512 + lid * 8);
        UNROLL for (int mt = 0; mt < 4; ++mt) {
            union { bf16x8 v; uint4 u; } afu;
            afu.u.x = pk2t(acc6[mt][0], acc6[mt][1]);
            afu.u.y = pk2t(acc6[mt][2], acc6[mt][3]);
            afu.u.z = (lid < 16) ? 0x00003f80u : 0u;   // k4 = 1.0
            afu.u.w = 0u;
            const long long erow = eBase + (long long)wid * 64 + mt * 16 + g * 4;
            UNROLL for (int nt = 0; nt < 4; ++nt) {
                f32x4 c = z;
                PRIO_HI;
                c = mfma1(afu.v, wf[nt], c);
                PRIO_LO;
                const int colv = nt * 16 + lr;     // C: col = lane&15 = class
                UNROLL for (int r = 0; r < 4; ++r) {
                    const long long ge = erow + r; // C: row = edge
                    if (colv < 51 && ge < E) out[ge * 51 + colv] = c[r];
                }
            }
        }

        if (ee < E) out_rel[ee] = (float)rel[e];
    }
}

extern "C" void kernel_launch(void* const* d_in, const int* in_sizes, int n_in,
                              void* d_out, int out_size, void* d_ws, size_t ws_size,
                              hipStream_t stream) {
    const float* obj   = (const float*)d_in[0];
    const int*   rel   = (const int*)  d_in[1];
    const int*   pairs = (const int*)  d_in[2];
    const float* oW0 = (const float*)d_in[3];
    const float* ob0 = (const float*)d_in[4];
    const float* oW1 = (const float*)d_in[5];
    const float* ob1 = (const float*)d_in[6];
    const float* oW2 = (const float*)d_in[7];
    const float* ob2 = (const float*)d_in[8];
    const float* oW3 = (const float*)d_in[9];
    const float* ob3 = (const float*)d_in[10];
    const float* rW0 = (const float*)d_in[11];
    const float* rb0 = (const float*)d_in[12];
    const float* rW1 = (const float*)d_in[13];
    const float* rb1 = (const float*)d_in[14];
    const float* rW2 = (const float*)d_in[15];
    const float* rb2 = (const float*)d_in[16];

    const int E = in_sizes[1];
    float* out     = (float*)d_out;
    float* out_rel = out + (size_t)E * 51;
    unsigned short* wsp = (unsigned short*)d_ws;

    hipLaunchKernelGGL(sg_prep, dim3(70), dim3(256), 0, stream,
                       oW0, ob0, oW1, oW2, oW3,
                       rW0, rb0, rW1, rb1, rW2, rb2, wsp);

    const int T = (E + 511) / 512;
    const int blocks = (T < 1024) ? T : 1024;   // persistent grid-stride
    hipLaunchKernelGGL(sg_mfma, dim3(blocks), dim3(512), 0, stream,
                       obj, rel, pairs, wsp,
                       ob1, ob2, ob3,
                       out, out_rel, E);
}

// Round 24
// 165.368 us; speedup vs baseline: 1.6642x; 1.6642x over previous
//
#include <hip/hip_runtime.h>

// SceneGraphModel, single-bf16 MFMA, barrier-free per-wave pipeline.
// Round-24 (base r21; r23 persistence regressed, reverted): RFO-FREE
// WRITEOUT. r23's counters exposed FETCH=402MB ~= out size (408MB): the
// misaligned 204B output rows write-miss every 64B line -> L2 RFO-fetches
// the whole output from HBM (+127MB partial-line evictions). True traffic
// ~950MB -> r21's 177.5us was ~85% of achievable BW. Fix: per 16-edge
// group, out region = exactly 51 whole 64B lines; stage C into per-wave
// LDS (3264B of the 4KB sF) then dump as 204 dense uint4 stores (16 full
// lines/instr) -> no RFO. Partial last tile keeps guarded scalar path.
// History: r5 nt-store amp; r6/r12/r19 spills; r15 occupancy falsified;
// r16 weights->LDS -11; r17 null; r18 wt-stationary -8; r20 unclamp worse;
// r21 block512 177.5 (best); r22 tail-wt-LDS +7.3; r23 persistent +98.

typedef __attribute__((ext_vector_type(8))) short bf16x8;   // 8 bf16 = 4 VGPR
typedef __attribute__((ext_vector_type(4))) float f32x4;

#define UNROLL _Pragma("unroll")
#define PRIO_HI __builtin_amdgcn_s_setprio(1)
#define PRIO_LO __builtin_amdgcn_s_setprio(0)

__device__ __forceinline__ unsigned fbits(float x) {
    union { float f; unsigned u; } v; v.f = x; return v.u;
}
// pack two f32 -> two bf16 (truncation; rel err 2^-8, fine vs thresholds)
__device__ __forceinline__ unsigned pk2t(float a, float b) {
    return (fbits(a) >> 16) | (fbits(b) & 0xffff0000u);
}
__device__ __forceinline__ unsigned short bf16rne(float x) {
    unsigned u = fbits(x);
    unsigned r = u + 0x7fffu + ((u >> 16) & 1u);
    return (unsigned short)(r >> 16);
}

__device__ __forceinline__ f32x4 mfma1(bf16x8 a, bf16x8 b, f32x4 acc) {
    return __builtin_amdgcn_mfma_f32_16x16x32_bf16(a, b, acc, 0, 0, 0);
}

__device__ __forceinline__ f32x4 bias4(const float* __restrict__ b, int nt, int g) {
    const float4 v = *(const float4*)(b + nt * 16 + g * 4);
    f32x4 r; r[0] = v.x; r[1] = v.y; r[2] = v.z; r[3] = v.w; return r;
}

// Store one lane's 4 consecutive-k values (bf16) into B-frag-order LDS tile.
// Element (row lr, k) lives at short index (lr + 16*(k>>3))*8 + (k&7).
__device__ __forceinline__ void chunk_store(unsigned short* __restrict__ tile,
                                            int lr, int klb, f32x4 a) {
    uint2 v; v.x = pk2t(a[0], a[1]); v.y = pk2t(a[2], a[3]);
    const int lanep = lr + 16 * (klb >> 3);
    *(uint2*)(tile + lanep * 8 + (klb & 7)) = v;
}

// B-frag load where k16..31 is the constant bias pattern: lanes g<2 read the
// staged k0..15; lane g==2 composes (k16=1.0,0..), g==3 all zeros.
__device__ __forceinline__ bf16x8 frag_or_const(const unsigned short* __restrict__ tile,
                                                int g, int lid, unsigned k16w) {
    union { bf16x8 v; uint4 u; } t;
    if (g < 2) {
        t.u = *(const uint4*)(tile + lid * 8);
    } else {
        t.u.x = k16w; t.u.y = 0u; t.u.z = 0u; t.u.w = 0u;
    }
    return t.v;
}

// ---- weight prep: bf16(RNE) + fragment-swizzle into d_ws ----
// frag element: lane l holds W[k][n], k = kt*32 + (l>>4)*8 + j, n = nt*16 + (l&15)
// W0 @0 (8 nt, k=16 row carries ob0), W1 @4096, W2 @12288, W3 @14336,
// W7 (rW2/rb2) B-frags @14848 (4 nt; k0-3 = rW2, k4 = rb2),
// W5 (rW0/rb0) @16896 (k0-15 = rW0, k16 = rb0), W6 (rW1/rb1) @17408.
__global__ __launch_bounds__(256) void sg_prep(
    const float* __restrict__ oW0, const float* __restrict__ ob0,
    const float* __restrict__ oW1, const float* __restrict__ oW2,
    const float* __restrict__ oW3,
    const float* __restrict__ rW0, const float* __restrict__ rb0,
    const float* __restrict__ rW1, const float* __restrict__ rb1,
    const float* __restrict__ rW2, const float* __restrict__ rb2,
    unsigned short* __restrict__ wsp)
{
    const int idx = blockIdx.x * 256 + threadIdx.x;
    if (idx >= 17920) return;
    if (idx >= 16896) {   // W5 / W6 tail-layer frags
        const int t2 = idx - 16896;
        const int tile = t2 >> 9;
        const int l = (t2 >> 3) & 63, j = t2 & 7;
        const int k = (l >> 4) * 8 + j;
        const int n = l & 15;
        float v = 0.0f;
        if (tile == 0) {          // 16->8: rW0 [16x8], rb0
            if (n < 8) { if (k < 16) v = rW0[k * 8 + n]; else if (k == 16) v = rb0[n]; }
        } else {                  // 8->4: rW1 [8x4], rb1
            if (n < 4) { if (k < 8) v = rW1[k * 4 + n]; else if (k == 16) v = rb1[n]; }
        }
        wsp[idx] = bf16rne(v);
        return;
    }
    if (idx >= 14848) {   // final-layer B-frags: B[k][n], n = class col
        const int t2 = idx - 14848;
        const int nt = t2 >> 9;
        const int l = (t2 >> 3) & 63, j = t2 & 7;
        const int k = (l >> 4) * 8 + j;
        const int n = nt * 16 + (l & 15);
        float v = 0.0f;
        if (n < 51) {
            if (k < 4)       v = rW2[k * 51 + n];
            else if (k == 4) v = rb2[n];
        }
        wsp[idx] = bf16rne(v);
        return;
    }
    int t = idx, K, N, kt, nt;
    const float* W;
    bool isW0 = false;
    if (t < 4096)        { W = oW0; K = 16;  N = 128; kt = 0; nt = t >> 9; isW0 = true; }
    else if (t < 12288)  { t -= 4096;  W = oW1; K = 128; N = 64; int f = t >> 9; kt = f >> 2; nt = f & 3; }
    else if (t < 14336)  { t -= 12288; W = oW2; K = 64;  N = 32; int f = t >> 9; kt = f >> 1; nt = f & 1; }
    else                 { t -= 14336; W = oW3; K = 32;  N = 16; kt = 0; nt = 0; }
    const int lid = (t >> 3) & 63, j = t & 7;
    const int k = kt * 32 + (lid >> 4) * 8 + j;
    const int n = nt * 16 + (lid & 15);
    float w = 0.0f;
    if (k < K)                w = W[(size_t)k * N + n];
    else if (isW0 && k == 16) w = ob0[n];          // bias row (h0 k=16 staged as 1.0)
    wsp[idx] = bf16rne(w);
}

__global__ __launch_bounds__(512, 4) void sg_mfma(
    const float* __restrict__ obj, const int* __restrict__ rel,
    const int* __restrict__ pairs,
    const unsigned short* __restrict__ wsp,
    const float* __restrict__ ob1, const float* __restrict__ ob2,
    const float* __restrict__ ob3,
    float* __restrict__ out, float* __restrict__ out_rel, int E)
{
    // LDS: [0,24K) block-shared W0+W1 frags; [24K,56K) per-wave 4 KB frag
    // buffers. 56 KB/block = 2 blocks/CU, 4 waves/SIMD.
    __shared__ unsigned char smem[24576 + 8 * 4096];
    const int tid = threadIdx.x;
    const int lid = tid & 63;
    const int wid = tid >> 6;
    const int g = lid >> 4, lr = lid & 15;
    unsigned short* wL = (unsigned short*)smem;
    unsigned short* sF = (unsigned short*)(smem + 24576 + wid * 4096);
    const unsigned k16w = (g == 2) ? 0x00003f80u : 0u;   // bf16(1.0) at k16

    // ---- cooperative stage of W0+W1 frags (24 KB = 1536 uint4) ----
    {
        const uint4* src = (const uint4*)wsp;
        uint4* dst = (uint4*)smem;
        UNROLL for (int i = 0; i < 3; ++i)
            dst[tid + i * 512] = src[tid + i * 512];
    }

    const long long eBase = (long long)blockIdx.x * 512;
    const long long ee = eBase + tid;
    const int e = (ee < E) ? (int)ee : (E - 1);

    // ---- stage h0 k0..15 only (k16..31 composed in registers at read) ----
    {
        const int2 pr = *(const int2*)(pairs + 2 * e);
        const float4* pa = (const float4*)(obj + (size_t)pr.x * 8);
        const float4* pb = (const float4*)(obj + (size_t)pr.y * 8);
        const float4 v0 = pa[0], v1 = pa[1], v2 = pb[0], v3 = pb[1];
        uint4 c0, c1;
        c0.x = pk2t(v0.x, v0.y); c0.y = pk2t(v0.z, v0.w);
        c0.z = pk2t(v1.x, v1.y); c0.w = pk2t(v1.z, v1.w);
        c1.x = pk2t(v2.x, v2.y); c1.y = pk2t(v2.z, v2.w);
        c1.z = pk2t(v3.x, v3.y); c1.w = pk2t(v3.z, v3.w);
        unsigned short* dh = sF + g * 512 + lr * 8;
        *(uint4*)(dh)       = c0;   // k 0..7
        *(uint4*)(dh + 128) = c1;   // k 8..15
    }

    __syncthreads();   // weights staged

    // hoist h0 B-frags (constant across all layer-1 tiles); g>=2 = const half
    bf16x8 a0[4];
    UNROLL for (int m = 0; m < 4; ++m)
        a0[m] = frag_or_const(sF + m * 512, g, lid, k16w);

    // ---- layers 1+2 fused over h1 32-col chunks (weight-stationary) ----
    f32x4 acc2[4][4];
    UNROLL for (int m = 0; m < 4; ++m)
        UNROLL for (int n2 = 0; n2 < 4; ++n2) acc2[m][n2] = bias4(ob1, n2, g);

    const f32x4 z = {0.0f, 0.0f, 0.0f, 0.0f};

    for (int kt2 = 0; kt2 < 4; ++kt2) {
        // layer1: 2 weight frags loaded ONCE, reused across all 4 m-tiles
        const bf16x8 w0a = *(const bf16x8*)(wL + (kt2 * 2 + 0) * 512 + lid * 8);
        const bf16x8 w0b = *(const bf16x8*)(wL + (kt2 * 2 + 1) * 512 + lid * 8);
        UNROLL for (int m = 0; m < 4; ++m) {
            f32x4 a = z, b = z;
            PRIO_HI;
            a = mfma1(w0a, a0[m], a);
            b = mfma1(w0b, a0[m], b);
            PRIO_LO;
            UNROLL for (int jr = 0; jr < 4; ++jr) {
                a[jr] = fmaxf(a[jr], 0.0f);
                b[jr] = fmaxf(b[jr], 0.0f);
            }
            chunk_store(sF + m * 512, lr, g * 4, a);
            chunk_store(sF + m * 512, lr, 16 + g * 4, b);
        }
        // layer2: h1 frags into regs once; weights n2-outer (4 reads, not 16)
        bf16x8 ah[4];
        UNROLL for (int m = 0; m < 4; ++m)
            ah[m] = *(const bf16x8*)(sF + m * 512 + lid * 8);
        UNROLL for (int n2 = 0; n2 < 4; ++n2) {
            const bf16x8 w = *(const bf16x8*)(wL + 4096 + (kt2 * 4 + n2) * 512 + lid * 8);
            PRIO_HI;
            UNROLL for (int m = 0; m < 4; ++m)
                acc2[m][n2] = mfma1(w, ah[m], acc2[m][n2]);
            PRIO_LO;
        }
    }

    // relu h2
    UNROLL for (int m = 0; m < 4; ++m)
        UNROLL for (int n2 = 0; n2 < 4; ++n2)
            UNROLL for (int jr = 0; jr < 4; ++jr)
                acc2[m][n2][jr] = fmaxf(acc2[m][n2][jr], 0.0f);

    // ---- layer 3 over h2 32-col chunks (weights hoisted, global/L1) ----
    f32x4 acc3[4][2];
    UNROLL for (int m = 0; m < 4; ++m)
        UNROLL for (int n3 = 0; n3 < 2; ++n3) acc3[m][n3] = bias4(ob2, n3, g);

    UNROLL for (int kt3 = 0; kt3 < 2; ++kt3) {
        UNROLL for (int m = 0; m < 4; ++m)
            UNROLL for (int ntl = 0; ntl < 2; ++ntl)
                chunk_store(sF + m * 512, lr, ntl * 16 + g * 4, acc2[m][2 * kt3 + ntl]);
        bf16x8 ah3[4];
        UNROLL for (int m = 0; m < 4; ++m)
            ah3[m] = *(const bf16x8*)(sF + m * 512 + lid * 8);
        UNROLL for (int n3 = 0; n3 < 2; ++n3) {
            const bf16x8 w = *(const bf16x8*)(wsp + 12288 + (size_t)(kt3 * 2 + n3) * 512 + lid * 8);
            PRIO_HI;
            UNROLL for (int m = 0; m < 4; ++m)
                acc3[m][n3] = mfma1(w, ah3[m], acc3[m][n3]);
            PRIO_LO;
        }
    }

    // ---- layer 4 (32->16, linear) via MFMA (weight hoisted: 1 read) ----
    UNROLL for (int m = 0; m < 4; ++m) {
        UNROLL for (int n3 = 0; n3 < 2; ++n3) {
            UNROLL for (int jr = 0; jr < 4; ++jr)
                acc3[m][n3][jr] = fmaxf(acc3[m][n3][jr], 0.0f);   // relu h3
            chunk_store(sF + m * 512, lr, n3 * 16 + g * 4, acc3[m][n3]);
        }
    }
    const bf16x8 w4 = *(const bf16x8*)(wsp + 14336 + lid * 8);
    f32x4 acc4[4];
    UNROLL for (int m = 0; m < 4; ++m) {
        bf16x8 ah = *(const bf16x8*)(sF + m * 512 + lid * 8);
        PRIO_HI;
        acc4[m] = mfma1(w4, ah, bias4(ob3, 0, g));
        PRIO_LO;
    }

    // hoist tail weight frags
    const bf16x8 w5 = *(const bf16x8*)(wsp + 16896 + lid * 8);
    const bf16x8 w6 = *(const bf16x8*)(wsp + 17408 + lid * 8);

    // ---- layer 5 (16->8, relu): stage h4 k0..15; k16..31 const ----
    UNROLL for (int m = 0; m < 4; ++m)
        chunk_store(sF + m * 512, lr, g * 4, acc4[m]);
    f32x4 acc5[4];
    UNROLL for (int m = 0; m < 4; ++m) {
        bf16x8 b5 = frag_or_const(sF + m * 512, g, lid, k16w);
        PRIO_HI;
        acc5[m] = mfma1(w5, b5, z);                      // bias via k16 row
        PRIO_LO;
        UNROLL for (int r = 0; r < 4; ++r) acc5[m][r] = fmaxf(acc5[m][r], 0.0f);
    }

    // ---- layer 6 (8->4, relu): stage h5 (k8..15 genuine zeros) ----
    UNROLL for (int m = 0; m < 4; ++m)
        chunk_store(sF + m * 512, lr, g * 4, acc5[m]);
    f32x4 acc6[4];
    UNROLL for (int m = 0; m < 4; ++m) {
        bf16x8 b6 = frag_or_const(sF + m * 512, g, lid, k16w);
        PRIO_HI;
        acc6[m] = mfma1(w6, b6, z);
        PRIO_LO;
        UNROLL for (int r = 0; r < 4; ++r) acc6[m][r] = fmaxf(acc6[m][r], 0.0f);
    }

    // ---- final layer 4->51 via MFMA; RFO-free writeout ----
    // Full tiles: stage each 16-edge group's C (16 rows x 51 cols = 3264 B =
    // exactly 51 whole 64B lines) into per-wave LDS, then dump as 204 dense
    // uint4 stores (16 full lines per instruction) -> no L2 write-allocate.
    bf16x8 wf[4];
    UNROLL for (int nt = 0; nt < 4; ++nt)
        wf[nt] = *(const bf16x8*)(wsp + 14848 + (size_t)nt * 512 + lid * 8);
    const bool full = (eBase + 512 <= (long long)E);
    float* sO = (float*)sF;   // per-wave 4 KB, reuse (holds 816 f32)
    UNROLL for (int mt = 0; mt < 4; ++mt) {
        union { bf16x8 v; uint4 u; } afu;
        afu.u.x = pk2t(acc6[mt][0], acc6[mt][1]);
        afu.u.y = pk2t(acc6[mt][2], acc6[mt][3]);
        afu.u.z = (lid < 16) ? 0x00003f80u : 0u;   // k4 = 1.0
        afu.u.w = 0u;
        if (full) {
            UNROLL for (int nt = 0; nt < 4; ++nt) {
                f32x4 c = z;
                PRIO_HI;
                c = mfma1(afu.v, wf[nt], c);
                PRIO_LO;
                const int colv = nt * 16 + lr;     // C: col = lane&15 = class
                if (colv < 51) {
                    UNROLL for (int r = 0; r < 4; ++r)
                        sO[(g * 4 + r) * 51 + colv] = c[r];   // row-major stage
                }
            }
            // dump: 816 f32 = 204 uint4, contiguous + 64B-line-exact
            const size_t gBase = (size_t)(eBase + (long long)wid * 64 + mt * 16) * 51;
            uint4* o4 = (uint4*)(out + gBase);
            const uint4* s4 = (const uint4*)sO;
            UNROLL for (int rd = 0; rd < 4; ++rd) {
                const int idx = rd * 64 + lid;
                if (idx < 204) o4[idx] = s4[idx];
            }
        } else {
            // partial tail tile: guarded scalar path (unchanged math)
            const long long erow = eBase + (long long)wid * 64 + mt * 16 + g * 4;
            UNROLL for (int nt = 0; nt < 4; ++nt) {
                f32x4 c = z;
                PRIO_HI;
                c = mfma1(afu.v, wf[nt], c);
                PRIO_LO;
                const int colv = nt * 16 + lr;
                UNROLL for (int r = 0; r < 4; ++r) {
                    const long long ge = erow + r;
                    if (colv < 51 && ge < E) out[ge * 51 + colv] = c[r];
                }
            }
        }
    }

    if (ee < E) out_rel[ee] = (float)rel[e];
}

extern "C" void kernel_launch(void* const* d_in, const int* in_sizes, int n_in,
                              void* d_out, int out_size, void* d_ws, size_t ws_size,
                              hipStream_t stream) {
    const float* obj   = (const float*)d_in[0];
    const int*   rel   = (const int*)  d_in[1];
    const int*   pairs = (const int*)  d_in[2];
    const float* oW0 = (const float*)d_in[3];
    const float* ob0 = (const float*)d_in[4];
    const float* oW1 = (const float*)d_in[5];
    const float* ob1 = (const float*)d_in[6];
    const float* oW2 = (const float*)d_in[7];
    const float* ob2 = (const float*)d_in[8];
    const float* oW3 = (const float*)d_in[9];
    const float* ob3 = (const float*)d_in[10];
    const float* rW0 = (const float*)d_in[11];
    const float* rb0 = (const float*)d_in[12];
    const float* rW1 = (const float*)d_in[13];
    const float* rb1 = (const float*)d_in[14];
    const float* rW2 = (const float*)d_in[15];
    const float* rb2 = (const float*)d_in[16];

    const int E = in_sizes[1];
    float* out     = (float*)d_out;
    float* out_rel = out + (size_t)E * 51;
    unsigned short* wsp = (unsigned short*)d_ws;

    hipLaunchKernelGGL(sg_prep, dim3(70), dim3(256), 0, stream,
                       oW0, ob0, oW1, oW2, oW3,
                       rW0, rb0, rW1, rb1, rW2, rb2, wsp);

    const int blocks = (E + 511) / 512;
    hipLaunchKernelGGL(sg_mfma, dim3(blocks), dim3(512), 0, stream,
                       obj, rel, pairs, wsp,
                       ob1, ob2, ob3,
                       out, out_rel, E);
}